// Round 3
// baseline (318.525 us; speedup 1.0000x reference)
//
#include <hip/hip_runtime.h>

// FWHT along axis 1 of (64, 1024, 512) fp32, unnormalized (a+b, a-b), h=1..512.
// Round 3: two streaming passes. H_1024 factors into commuting stages on
// distinct row-index bits:
//   kernel 1: bits 0-4 (h=1..16)  -> butterflies within contiguous 32-row
//             groups; each block owns a fully contiguous 64 KB chunk.
//   kernel 2: bits 5-9 (h=32..512)-> butterflies at row stride 32; each block
//             owns 32 rows that are each a contiguous 2 KB (DRAM-page) chunk,
//             in-place on d_out.
// Round-2 lesson: one-pass tiling forces 64 B-granule HBM access (64 B per
// 32 KB stride) which caps at ~2.3 TB/s. Both passes here stream at >=512 B
// per instruction / >=2 KB per chunk; the 128 MB intermediate fits in the
// 256 MiB Infinity Cache, so real HBM traffic stays ~260 MB.
// No LDS, no barriers in either kernel.

constexpr int NB = 64;    // batch
constexpr int NR = 1024;  // transform length (axis 1)
constexpr int ND = 512;   // inner dim
constexpr int TPB = 256;  // threads; each owns a float2 column pair

// ---- Kernel 1: H_32 on row bits 0-4 (contiguous pairs) ----
// Block (b, q): rows [32q, 32q+32), all 512 cols. Tile = contiguous 64 KB.
__global__ __launch_bounds__(TPB, 4)
void fwht_lo(const float* __restrict__ x, float* __restrict__ y) {
    const int b = blockIdx.x & 63;
    const int q = blockIdx.x >> 6;  // [0,32)
    const size_t base = ((size_t)b * NR + (size_t)q * 32) * ND + threadIdx.x * 2;

    float2 u[32];
#pragma unroll
    for (int r = 0; r < 32; ++r)
        u[r] = *reinterpret_cast<const float2*>(x + base + (size_t)r * ND);

#pragma unroll
    for (int hb = 1; hb < 32; hb <<= 1) {
#pragma unroll
        for (int r = 0; r < 32; ++r) {
            if ((r & hb) == 0) {
                const int k = r | hb;
                const float2 a = u[r], c = u[k];
                u[r] = make_float2(a.x + c.x, a.y + c.y);
                u[k] = make_float2(a.x - c.x, a.y - c.y);
            }
        }
    }

#pragma unroll
    for (int r = 0; r < 32; ++r)
        *reinterpret_cast<float2*>(y + base + (size_t)r * ND) = u[r];
}

// ---- Kernel 2: H_32 on row bits 5-9 (stride-32 pairs), in-place on y ----
// Block (b, q): rows {q + 32 i : i in [0,32)}, all 512 cols.
// Each (row, col-pair) element is owned by exactly one thread -> in-place safe.
__global__ __launch_bounds__(TPB, 4)
void fwht_hi(float* __restrict__ y) {
    const int b = blockIdx.x & 63;
    const int q = blockIdx.x >> 6;  // [0,32)
    const size_t base = ((size_t)b * NR + (size_t)q) * ND + threadIdx.x * 2;

    float2 u[32];
#pragma unroll
    for (int i = 0; i < 32; ++i)
        u[i] = *reinterpret_cast<const float2*>(y + base + (size_t)(i * 32) * ND);

#pragma unroll
    for (int hb = 1; hb < 32; hb <<= 1) {
#pragma unroll
        for (int i = 0; i < 32; ++i) {
            if ((i & hb) == 0) {
                const int k = i | hb;
                const float2 a = u[i], c = u[k];
                u[i] = make_float2(a.x + c.x, a.y + c.y);
                u[k] = make_float2(a.x - c.x, a.y - c.y);
            }
        }
    }

#pragma unroll
    for (int i = 0; i < 32; ++i)
        *reinterpret_cast<float2*>(y + base + (size_t)(i * 32) * ND) = u[i];
}

extern "C" void kernel_launch(void* const* d_in, const int* in_sizes, int n_in,
                              void* d_out, int out_size, void* d_ws, size_t ws_size,
                              hipStream_t stream) {
    const float* x = (const float*)d_in[0];
    float* y = (float*)d_out;
    const int grid = NB * (NR / 32);  // 2048 blocks each
    fwht_lo<<<dim3(grid), dim3(TPB), 0, stream>>>(x, y);
    fwht_hi<<<dim3(grid), dim3(TPB), 0, stream>>>(y);
}